// Round 1
// baseline (115.789 us; speedup 1.0000x reference)
//
#include <hip/hip_runtime.h>
#include <math.h>

namespace {

constexpr int KK = 4;
constexpr int DD = 16;
constexpr int BLOCK = 256;
constexpr int PTS = 4;                       // points per thread
constexpr float LOG2PI = 1.8378770664093453f;
constexpr float INV_SQRT2 = 0.70710678118654752f;   // folds the 0.5 into Linv

__global__ __launch_bounds__(BLOCK, 4)      // cap <=128 VGPR -> >=4 waves/SIMD
void gmm_energy(const float* __restrict__ z, const float* __restrict__ phi,
                const float* __restrict__ mu, const float* __restrict__ L,
                float* __restrict__ out, int N)
{
    __shared__ float sLinv[KK][DD][DD];   // (1/sqrt2) * inverse of upper-tri L_k
    __shared__ float sW[KK][DD];          // w_k = sLinv_k * mu_k (already scaled)
    __shared__ float sC0[KK];             // log(phi_k) - 0.5*D*log(2pi) - logdet

    const int tid = threadIdx.x;
    const int base = blockIdx.x * (BLOCK * PTS) + tid * PTS;

    // ---- issue z loads FIRST: ~900-cycle HBM latency overlaps the preamble
    //      (wave 0 computes the inversion; waves 1-3 sleep at the barrier with
    //      their loads already in flight) ----
    float zr[PTS][DD];
    if (base + PTS <= N) {
        #pragma unroll
        for (int p = 0; p < PTS; ++p) {
            const float4* zp = reinterpret_cast<const float4*>(z + (size_t)(base + p) * DD);
            #pragma unroll
            for (int c = 0; c < 4; ++c) {
                float4 v = zp[c];
                zr[p][c * 4 + 0] = v.x;
                zr[p][c * 4 + 1] = v.y;
                zr[p][c * 4 + 2] = v.z;
                zr[p][c * 4 + 3] = v.w;
            }
        }
    } else {
        #pragma unroll
        for (int p = 0; p < PTS; ++p) {
            if (base + p < N) {
                const float4* zp = reinterpret_cast<const float4*>(z + (size_t)(base + p) * DD);
                #pragma unroll
                for (int c = 0; c < 4; ++c) {
                    float4 v = zp[c];
                    zr[p][c * 4 + 0] = v.x;
                    zr[p][c * 4 + 1] = v.y;
                    zr[p][c * 4 + 2] = v.z;
                    zr[p][c * 4 + 3] = v.w;
                }
            } else {
                #pragma unroll
                for (int d = 0; d < DD; ++d) zr[p][d] = 0.0f;
            }
        }
    }

    // ---- per-block prep (wave 0 only): invert the 4 upper-triangular 16x16
    //      factors via back substitution. v_rcp_f32 instead of precise fdiv
    //      (16 independent rcps pipeline; chain cost drops ~3x). ----
    if (tid < KK * DD) {
        const int k = tid >> 4;
        const int j = tid & 15;
        const float* __restrict__ Lk = L + k * DD * DD;

        float rd[DD];
        #pragma unroll
        for (int i = 0; i < DD; ++i)
            rd[i] = __builtin_amdgcn_rcpf(Lk[i * DD + i]);

        float xv[DD];
        #pragma unroll
        for (int m = 0; m < DD; ++m) xv[m] = 0.0f;
        #pragma unroll
        for (int i = DD - 1; i >= 0; --i) {
            float s = (i == j) ? 1.0f : 0.0f;
            #pragma unroll
            for (int m = i + 1; m < DD; ++m)
                s = fmaf(-Lk[i * DD + m], xv[m], s);      // xv[m]==0 for m>j
            xv[i] = (i <= j) ? (s * rd[i]) : 0.0f;
        }
        #pragma unroll
        for (int i = 0; i < DD; ++i)
            sLinv[k][i][j] = xv[i] * INV_SQRT2;

        // Same wave: LDS writes above are ordered before these reads via
        // lgkmcnt -- no __syncthreads needed between the two phases.
        const int i2 = j;
        float w = 0.0f;
        #pragma unroll
        for (int jj = 0; jj < DD; ++jj)
            w = fmaf(sLinv[k][i2][jj], mu[k * DD + jj], w);
        sW[k][i2] = w;
    }
    if (tid < KK) {
        float logdet = 0.0f;
        #pragma unroll
        for (int i = 0; i < DD; ++i)
            logdet += __logf(L[tid * DD * DD + i * DD + i]);
        sC0[tid] = __logf(phi[tid]) - 8.0f * LOG2PI - logdet;
    }
    __syncthreads();                       // the ONLY barrier

    // ---- per-component Mahalanobis via scaled triangular matvec ----
    // acc = (1/sqrt2) * (Linv_row_i . z - w_i); q = sum acc^2 = 0.5*Mahalanobis
    float lg[PTS][KK];
    #pragma unroll
    for (int k = 0; k < KK; ++k) {
        float q[PTS];
        #pragma unroll
        for (int p = 0; p < PTS; ++p) q[p] = 0.0f;
        #pragma unroll
        for (int i = 0; i < DD; ++i) {
            const float wk = sW[k][i];
            const float cdiag = sLinv[k][i][i];
            float acc[PTS];
            #pragma unroll
            for (int p = 0; p < PTS; ++p)
                acc[p] = fmaf(cdiag, zr[p][i], -wk);       // init folded into fma
            #pragma unroll
            for (int j = i + 1; j < DD; ++j) {
                const float cf = sLinv[k][i][j];           // uniform LDS broadcast
                #pragma unroll
                for (int p = 0; p < PTS; ++p)
                    acc[p] = fmaf(cf, zr[p][j], acc[p]);
            }
            #pragma unroll
            for (int p = 0; p < PTS; ++p)
                q[p] = fmaf(acc[p], acc[p], q[p]);
        }
        const float c0 = sC0[k];
        #pragma unroll
        for (int p = 0; p < PTS; ++p)
            lg[p][k] = c0 - q[p];                          // 0.5 already folded
    }

    // ---- logsumexp over K=4, negate, store ----
    float e[PTS];
    #pragma unroll
    for (int p = 0; p < PTS; ++p) {
        float m01 = fmaxf(lg[p][0], lg[p][1]);
        float m23 = fmaxf(lg[p][2], lg[p][3]);
        float m = fmaxf(m01, m23);
        float s = __expf(lg[p][0] - m) + __expf(lg[p][1] - m)
                + __expf(lg[p][2] - m) + __expf(lg[p][3] - m);
        e[p] = -(m + __logf(s));
    }

    if (base + PTS <= N) {
        float4 res;
        res.x = e[0]; res.y = e[1]; res.z = e[2]; res.w = e[3];
        *reinterpret_cast<float4*>(out + base) = res;
    } else {
        #pragma unroll
        for (int p = 0; p < PTS; ++p) {
            if (base + p < N) out[base + p] = e[p];
        }
    }
}

} // namespace

extern "C" void kernel_launch(void* const* d_in, const int* in_sizes, int n_in,
                              void* d_out, int out_size, void* d_ws, size_t ws_size,
                              hipStream_t stream) {
    const float* z   = (const float*)d_in[0];   // [N,16]
    const float* phi = (const float*)d_in[1];   // [4]
    const float* mu  = (const float*)d_in[2];   // [4,16]
    const float* L   = (const float*)d_in[3];   // [4,16,16] upper-triangular
    float* out = (float*)d_out;                 // [N]
    const int N = in_sizes[0] / DD;
    const int grid = (N + BLOCK * PTS - 1) / (BLOCK * PTS);
    gmm_energy<<<grid, BLOCK, 0, stream>>>(z, phi, mu, L, out, N);
}

// Round 2
// 113.664 us; speedup vs baseline: 1.0187x; 1.0187x over previous
//
#include <hip/hip_runtime.h>
#include <math.h>

namespace {

constexpr int KK = 4;
constexpr int DD = 16;
constexpr int BLOCK = 256;
constexpr int PTS = 2;                       // points per thread (small -> high occupancy)
constexpr float LOG2PI = 1.8378770664093453f;
constexpr float INV_SQRT2 = 0.70710678118654752f;   // folds the 0.5 into Linv

// Workspace layout (floats):
//   [0    .. 1023]  Linv_scaled[k][i][j]   ((1/sqrt2) * inv(L_k), upper-tri)
//   [1024 .. 1087]  W[k][i] = Linv_scaled_k . mu_k
//   [1088 .. 1091]  C0[k]   = log(phi_k) - 8*log(2pi) - logdet_k
constexpr int WOFF_W  = KK * DD * DD;        // 1024
constexpr int WOFF_C0 = WOFF_W + KK * DD;    // 1088

// ---------------------------------------------------------------------------
// Prep kernel: 1 block, 64 threads. Thread (k,j) computes column j of
// inv(L_k) by back substitution (precise divide -- off the hot path).
// ---------------------------------------------------------------------------
__global__ void gmm_prep(const float* __restrict__ phi, const float* __restrict__ mu,
                         const float* __restrict__ L, float* __restrict__ ws)
{
    const int tid = threadIdx.x;             // 0..63
    const int k = tid >> 4;
    const int j = tid & 15;
    const float* __restrict__ Lk = L + k * DD * DD;

    float xv[DD];
    #pragma unroll
    for (int m = 0; m < DD; ++m) xv[m] = 0.0f;
    #pragma unroll
    for (int i = DD - 1; i >= 0; --i) {
        float s = (i == j) ? 1.0f : 0.0f;
        #pragma unroll
        for (int m = i + 1; m < DD; ++m)
            s = fmaf(-Lk[i * DD + m], xv[m], s);      // xv[m]==0 for m>j
        xv[i] = (i <= j) ? (s / Lk[i * DD + i]) : 0.0f;
    }
    #pragma unroll
    for (int i = 0; i < DD; ++i)
        ws[k * DD * DD + i * DD + j] = xv[i] * INV_SQRT2;

    __syncthreads();   // one block, one CU: global writes above visible after barrier

    // Row j of W_k (thread's j reused as row index).
    float w = 0.0f;
    #pragma unroll
    for (int jj = 0; jj < DD; ++jj)
        w = fmaf(ws[k * DD * DD + j * DD + jj], mu[k * DD + jj], w);
    ws[WOFF_W + k * DD + j] = w;

    if (tid < KK) {
        float logdet = 0.0f;
        #pragma unroll
        for (int i = 0; i < DD; ++i)
            logdet += __logf(L[tid * DD * DD + i * DD + i]);
        ws[WOFF_C0 + tid] = __logf(phi[tid]) - 8.0f * LOG2PI - logdet;
    }
}

// ---------------------------------------------------------------------------
// Main kernel: no LDS, no barriers, no preamble. Every coefficient access is
// a uniform compile-time-constant offset from cw -> compiler emits batched
// s_load_dwordx4/x8/x16; inner-loop FMAs take the coefficient as an SGPR
// operand (zero VALU/DS cost for coefficient access).
// ---------------------------------------------------------------------------
__global__ __launch_bounds__(BLOCK, 4)
void gmm_energy(const float* __restrict__ z, const float* __restrict__ cw,
                float* __restrict__ out, int N)
{
    const int tid = threadIdx.x;
    const int base = blockIdx.x * (BLOCK * PTS) + tid * PTS;
    const bool full = (base + PTS <= N);

    // ---- load PTS rows of z (each row = 64 B = four float4 loads) ----
    float zr[PTS][DD];
    if (full) {
        #pragma unroll
        for (int p = 0; p < PTS; ++p) {
            const float4* zp = reinterpret_cast<const float4*>(z + (size_t)(base + p) * DD);
            #pragma unroll
            for (int c = 0; c < 4; ++c) {
                float4 v = zp[c];
                zr[p][c * 4 + 0] = v.x;
                zr[p][c * 4 + 1] = v.y;
                zr[p][c * 4 + 2] = v.z;
                zr[p][c * 4 + 3] = v.w;
            }
        }
    } else {
        #pragma unroll
        for (int p = 0; p < PTS; ++p) {
            if (base + p < N) {
                const float4* zp = reinterpret_cast<const float4*>(z + (size_t)(base + p) * DD);
                #pragma unroll
                for (int c = 0; c < 4; ++c) {
                    float4 v = zp[c];
                    zr[p][c * 4 + 0] = v.x;
                    zr[p][c * 4 + 1] = v.y;
                    zr[p][c * 4 + 2] = v.z;
                    zr[p][c * 4 + 3] = v.w;
                }
            } else {
                #pragma unroll
                for (int d = 0; d < DD; ++d) zr[p][d] = 0.0f;
            }
        }
    }

    // ---- per-component Mahalanobis via scaled triangular matvec ----
    // acc = (1/sqrt2)*(Linv_row_i . z) - w_i ; q = sum acc^2 = 0.5*Mahalanobis
    float lg[PTS][KK];
    #pragma unroll
    for (int k = 0; k < KK; ++k) {
        const float* __restrict__ Ck = cw + k * DD * DD;     // uniform -> SGPR
        const float* __restrict__ Wk = cw + WOFF_W + k * DD;
        float q[PTS];
        #pragma unroll
        for (int p = 0; p < PTS; ++p) q[p] = 0.0f;
        #pragma unroll
        for (int i = 0; i < DD; ++i) {
            const float wk = Wk[i];
            float acc[PTS];
            #pragma unroll
            for (int p = 0; p < PTS; ++p)
                acc[p] = fmaf(Ck[i * DD + i], zr[p][i], -wk);
            #pragma unroll
            for (int j = i + 1; j < DD; ++j) {
                const float cf = Ck[i * DD + j];
                #pragma unroll
                for (int p = 0; p < PTS; ++p)
                    acc[p] = fmaf(cf, zr[p][j], acc[p]);
            }
            #pragma unroll
            for (int p = 0; p < PTS; ++p)
                q[p] = fmaf(acc[p], acc[p], q[p]);
        }
        const float c0 = cw[WOFF_C0 + k];
        #pragma unroll
        for (int p = 0; p < PTS; ++p)
            lg[p][k] = c0 - q[p];                            // 0.5 already folded
    }

    // ---- logsumexp over K=4, negate, store ----
    float e[PTS];
    #pragma unroll
    for (int p = 0; p < PTS; ++p) {
        float m01 = fmaxf(lg[p][0], lg[p][1]);
        float m23 = fmaxf(lg[p][2], lg[p][3]);
        float m = fmaxf(m01, m23);
        float s = __expf(lg[p][0] - m) + __expf(lg[p][1] - m)
                + __expf(lg[p][2] - m) + __expf(lg[p][3] - m);
        e[p] = -(m + __logf(s));
    }

    if (full) {
        float2 res;
        res.x = e[0]; res.y = e[1];
        *reinterpret_cast<float2*>(out + base) = res;
    } else {
        #pragma unroll
        for (int p = 0; p < PTS; ++p) {
            if (base + p < N) out[base + p] = e[p];
        }
    }
}

} // namespace

extern "C" void kernel_launch(void* const* d_in, const int* in_sizes, int n_in,
                              void* d_out, int out_size, void* d_ws, size_t ws_size,
                              hipStream_t stream) {
    const float* z   = (const float*)d_in[0];   // [N,16]
    const float* phi = (const float*)d_in[1];   // [4]
    const float* mu  = (const float*)d_in[2];   // [4,16]
    const float* L   = (const float*)d_in[3];   // [4,16,16] upper-triangular
    float* out = (float*)d_out;                 // [N]
    float* ws  = (float*)d_ws;                  // >= 4368 B needed
    const int N = in_sizes[0] / DD;

    gmm_prep<<<1, 64, 0, stream>>>(phi, mu, L, ws);

    const int grid = (N + BLOCK * PTS - 1) / (BLOCK * PTS);
    gmm_energy<<<grid, BLOCK, 0, stream>>>(z, ws, out, N);
}